// Round 5
// baseline (198.504 us; speedup 1.0000x reference)
//
#include <hip/hip_runtime.h>
#include <math.h>

#define BB 64
#define NN 256
#define IN_F 128
#define OF 128
#define HH 4
#define NEG_SLOPE 0.2f

typedef __attribute__((ext_vector_type(8))) short short8;
typedef __attribute__((ext_vector_type(4))) float f32x4;

#define MFMA16(a, b, c) __builtin_amdgcn_mfma_f32_16x16x32_bf16(a, b, c, 0, 0, 0)

// float -> bf16 bits, round-to-nearest-even (finite)
__device__ inline unsigned short f2bf(float x) {
    unsigned u = __float_as_uint(x);
    u += 0x7fff + ((u >> 16) & 1);
    return (unsigned short)(u >> 16);
}

// ---------------- K0: qm -> u8 quadrant index; W/Wc transposes ----------------
// blocks [0,2048): qm (int pairs) -> qidx u8 (q.x*4+q.y)
// blocks [2048,2056): W[128k][512f] -> Wt[512f][128k] bf16
// blocks [2056,2088): Wc[512k][128c] -> Wct[128c][512k] bf16
__global__ __launch_bounds__(256) void k0_prep(const int* __restrict__ qm,
        const float* __restrict__ W, const float* __restrict__ Wc,
        unsigned char* __restrict__ qidx, unsigned short* __restrict__ Wt,
        unsigned short* __restrict__ Wct) {
    __shared__ float hl[16][516];
    int blk = blockIdx.x, t = threadIdx.x;
    if (blk < 2048) {
        const int4* qp = (const int4*)qm;
        size_t base = (size_t)blk * 1024;
#pragma unroll
        for (int it = 0; it < 4; it++) {
            size_t i4 = base + it * 256 + t;
            int4 v = qp[i4];            // two (x,y) pairs
            unsigned short pk = (unsigned short)((v.x * 4 + v.y) | ((v.z * 4 + v.w) << 8));
            ((unsigned short*)qidx)[i4] = pk;
        }
    } else if (blk < 2056) {
        int k0 = (blk - 2048) * 16;
#pragma unroll
        for (int it = 0; it < 8; it++) {         // stage 16x512 f32, coalesced
            int li = it * 256 + t;
            int row = li >> 7, col4 = li & 127;
            float4 v = ((const float4*)(W + (size_t)(k0 + row) * 512))[col4];
            *(float4*)&hl[row][col4 * 4] = v;
        }
        __syncthreads();
#pragma unroll
        for (int cc = 0; cc < 2; cc++) {         // write Wt rows: 32B contiguous per f
            int c = t * 2 + cc;
            short8 s0, s1;
#pragma unroll
            for (int k = 0; k < 8; k++) s0[k] = (short)f2bf(hl[k][c]);
#pragma unroll
            for (int k = 0; k < 8; k++) s1[k] = (short)f2bf(hl[k + 8][c]);
            unsigned short* dst = Wt + (size_t)c * 128 + k0;
            *(short8*)dst = s0;
            *(short8*)(dst + 8) = s1;
        }
    } else {
        int k0 = (blk - 2056) * 16;
#pragma unroll
        for (int it = 0; it < 2; it++) {         // stage 16x128 f32
            int li = it * 256 + t;
            int row = li >> 5, col4 = li & 31;
            float4 v = ((const float4*)(Wc + (size_t)(k0 + row) * 128))[col4];
            *(float4*)&hl[row][col4 * 4] = v;
        }
        __syncthreads();
        if (t < 128) {
            int c = t;
            short8 s0, s1;
#pragma unroll
            for (int k = 0; k < 8; k++) s0[k] = (short)f2bf(hl[k][c]);
#pragma unroll
            for (int k = 0; k < 8; k++) s1[k] = (short)f2bf(hl[k + 8][c]);
            unsigned short* dst = Wct + (size_t)c * 512 + k0;
            *(short8*)dst = s0;
            *(short8*)(dst + 8) = s1;
        }
    }
}

// ---------------- K1: Wht[f][n] = (h@W)^T via MFMA, packed 8B stores ----------
// grid = 512: b = l>>3, 32-node chunk n0 = (l&7)*32. 4 waves = 4 heads.
// D[n][f] orientation: A = h (row=cc=n, k-contig), B = Wt (col=cc=f, k-contig).
// Lane holds 4 consecutive n for fixed f -> 8B packed Wht store.
__global__ __launch_bounds__(256) void k1_wh(const float* __restrict__ h,
        const unsigned short* __restrict__ Wt, const float* __restrict__ a,
        const float* __restrict__ w_proj, const float* __restrict__ w_sim,
        unsigned short* __restrict__ Wht, float* __restrict__ ei,
        float* __restrict__ ej, float* __restrict__ sp, float* __restrict__ ss) {
    __shared__ __align__(16) unsigned char hs[8192];   // 32 rows x 256B, XOR-swizzled
    __shared__ float a1s[512], a2s[512], wps[128], wss[128];
    int l = blockIdx.x;
    int b = l >> 3, n0 = (l & 7) * 32;
    int t = threadIdx.x;
    for (int idx = t; idx < 512; idx += 256) {
        int hh = idx >> 7, f = idx & 127;
        a1s[idx] = a[hh * 256 + f];
        a2s[idx] = a[hh * 256 + 128 + f];
    }
    if (t < 128) { wps[t] = w_proj[t]; wss[t] = w_sim[t]; }
    {   // stage h rows n0..n0+31 as bf16, coalesced f32 loads
        const float4* hsrc = (const float4*)(h + ((size_t)b * NN + n0) * IN_F);
#pragma unroll
        for (int it = 0; it < 4; it++) {
            int li = it * 256 + t;
            float4 v = hsrc[li];
            int row = li >> 5, col4 = li & 31;
            ushort4 o;
            o.x = f2bf(v.x); o.y = f2bf(v.y); o.z = f2bf(v.z); o.w = f2bf(v.w);
            *(ushort4*)(hs + row * 256 + ((col4 * 8) ^ ((row & 7) << 4))) = o;
        }
    }
    __syncthreads();

    int w = t >> 6, lane = t & 63;
    int cc = lane & 15, g = lane >> 4;

    // A-frags from LDS: row = n-tile + cc, k = ks*32 + g*8 + e
    short8 bh[2][4];
#pragma unroll
    for (int tn = 0; tn < 2; tn++) {
        int row = tn * 16 + cc;
#pragma unroll
        for (int ks = 0; ks < 4; ks++)
            bh[tn][ks] = *(const short8*)(hs + row * 256 + ((ks * 64 + g * 16) ^ ((row & 7) << 4)));
    }

    float q[2][4][4] = {{{0.f}}};   // [tn][type][r], fully unrolled -> regs
    unsigned short* whb = Wht + (size_t)(b * HH + w) * OF * NN;

#pragma unroll
    for (int tf = 0; tf < 8; tf++) {
        int f = tf * 16 + cc;
        short8 aw[4];     // B-frags: Wt[f][k]
#pragma unroll
        for (int ks = 0; ks < 4; ks++)
            aw[ks] = *(const short8*)(Wt + (size_t)(w * 128 + f) * IN_F + ks * 32 + g * 8);
        f32x4 acc[2];
        acc[0] = (f32x4)(0.f); acc[1] = (f32x4)(0.f);
#pragma unroll
        for (int ks = 0; ks < 4; ks++) {
            acc[0] = MFMA16(bh[0][ks], aw[ks], acc[0]);
            acc[1] = MFMA16(bh[1][ks], aw[ks], acc[1]);
        }
        float c1 = a1s[w * 128 + f], c2 = a2s[w * 128 + f];
        float c3 = wps[f], c4 = wss[f];
#pragma unroll
        for (int tn = 0; tn < 2; tn++) {
            ushort4 o;      // 4 consecutive n for fixed f -> packed 8B store
            o.x = f2bf(acc[tn][0]); o.y = f2bf(acc[tn][1]);
            o.z = f2bf(acc[tn][2]); o.w = f2bf(acc[tn][3]);
            *(ushort4*)(whb + (size_t)f * NN + n0 + tn * 16 + g * 4) = o;
#pragma unroll
            for (int r = 0; r < 4; r++) {
                float v = acc[tn][r];
                q[tn][0][r] += v * c1; q[tn][1][r] += v * c2;
                q[tn][2][r] += v * c3; q[tn][3][r] += v * c4;
            }
        }
    }
    // reduce scalar dots across the 16 cc-lanes
#pragma unroll
    for (int tn = 0; tn < 2; tn++)
#pragma unroll
        for (int ty = 0; ty < 4; ty++)
#pragma unroll
            for (int r = 0; r < 4; r++) {
                float v = q[tn][ty][r];
                v += __shfl_xor(v, 1); v += __shfl_xor(v, 2);
                v += __shfl_xor(v, 4); v += __shfl_xor(v, 8);
                q[tn][ty][r] = v;
            }
    if (cc == 0) {
#pragma unroll
        for (int tn = 0; tn < 2; tn++) {
            size_t base = (size_t)(b * HH + w) * NN + n0 + tn * 16 + g * 4;
            *(float4*)&ei[base] = make_float4(q[tn][0][0], q[tn][0][1], q[tn][0][2], q[tn][0][3]);
            *(float4*)&ej[base] = make_float4(q[tn][1][0], q[tn][1][1], q[tn][1][2], q[tn][1][3]);
            *(float4*)&sp[base] = make_float4(q[tn][2][0], q[tn][2][1], q[tn][2][2], q[tn][2][3]);
            *(float4*)&ss[base] = make_float4(q[tn][3][0], q[tn][3][1], q[tn][3][2], q[tn][3][3]);
        }
    }
}

// ---------------- K2: e + softmax + MFMA PV + MFMA Wc + ELU (37.7KB LDS) ------
__global__ __launch_bounds__(256) void k2_fused(
        const float* __restrict__ proj, const float* __restrict__ sim,
        const unsigned char* __restrict__ qidx, const float* __restrict__ qbias,
        const float* __restrict__ ei, const float* __restrict__ ej,
        const float* __restrict__ sp, const float* __restrict__ ss,
        const unsigned short* __restrict__ Wht, const unsigned short* __restrict__ Wct,
        float* __restrict__ out) {
    __shared__ __align__(16) char at_lds[32768];   // attn bf16 [4][16][256] swizzled; later hp bf16[16][512]
    __shared__ __align__(16) float ejs[1024];
    __shared__ float eis[HH][16], sps[HH][16], sss[HH][16];
    __shared__ float qb_s[16];

    int l = blockIdx.x;                  // XCD-bijective remap: chunks of b co-located
    int xcd = l & 7, m = l >> 3;
    int b = xcd + ((m >> 4) << 3);
    int i0 = (m & 15) * 16;
    int t = threadIdx.x;
    int wave = t >> 6, lane = t & 63;

    for (int c = t; c < HH * NN; c += 256)
        ejs[c] = ej[(size_t)b * HH * NN + c];
    if (t < 64) {
        int hh = t >> 4, ii = t & 15;
        size_t base = ((size_t)b * HH + hh) * NN + i0 + ii;
        eis[hh][ii] = ei[base]; sps[hh][ii] = sp[base]; sss[hh][ii] = ss[base];
    }
    if (t < 16) qb_s[t] = qbias[t];
    __syncthreads();

    // ---- phase B: wave owns rows wave*4..+3; lane owns j = lane*4..+3
    int j0 = lane * 4;
    float4 P4[4], S4[4];
    unsigned qi[4];
#pragma unroll
    for (int rr = 0; rr < 4; rr++) {
        int i = i0 + wave * 4 + rr;
        size_t rb = ((size_t)b * NN + i) * NN + j0;
        P4[rr] = *(const float4*)&proj[rb];
        S4[rr] = *(const float4*)&sim[rb];
        qi[rr] = *(const unsigned*)(qidx + rb);
    }
#pragma unroll
    for (int rr = 0; rr < 4; rr++) {
        int ii = wave * 4 + rr;
        float qb0 = qb_s[qi[rr] & 15];
        float qb1 = qb_s[(qi[rr] >> 8) & 15];
        float qb2 = qb_s[(qi[rr] >> 16) & 15];
        float qb3 = qb_s[(qi[rr] >> 24) & 15];
        float e[HH][4];
#pragma unroll
        for (int hh = 0; hh < HH; hh++) {
            float4 ej4 = *(const float4*)&ejs[hh * 256 + j0];
            float bi = eis[hh][ii], spv = sps[hh][ii], ssv = sss[hh][ii];
            float x;
            x = bi + ej4.x; x = x > 0.f ? x : NEG_SLOPE * x; e[hh][0] = x + spv * P4[rr].x + ssv * S4[rr].x + qb0;
            x = bi + ej4.y; x = x > 0.f ? x : NEG_SLOPE * x; e[hh][1] = x + spv * P4[rr].y + ssv * S4[rr].y + qb1;
            x = bi + ej4.z; x = x > 0.f ? x : NEG_SLOPE * x; e[hh][2] = x + spv * P4[rr].z + ssv * S4[rr].z + qb2;
            x = bi + ej4.w; x = x > 0.f ? x : NEG_SLOPE * x; e[hh][3] = x + spv * P4[rr].w + ssv * S4[rr].w + qb3;
        }
        float mx[HH];
#pragma unroll
        for (int hh = 0; hh < HH; hh++)
            mx[hh] = fmaxf(fmaxf(e[hh][0], e[hh][1]), fmaxf(e[hh][2], e[hh][3]));
#pragma unroll
        for (int off = 32; off; off >>= 1)
#pragma unroll
            for (int hh = 0; hh < HH; hh++)
                mx[hh] = fmaxf(mx[hh], __shfl_xor(mx[hh], off));
        float s[HH];
#pragma unroll
        for (int hh = 0; hh < HH; hh++) {
            e[hh][0] = __expf(e[hh][0] - mx[hh]);
            e[hh][1] = __expf(e[hh][1] - mx[hh]);
            e[hh][2] = __expf(e[hh][2] - mx[hh]);
            e[hh][3] = __expf(e[hh][3] - mx[hh]);
            s[hh] = (e[hh][0] + e[hh][1]) + (e[hh][2] + e[hh][3]);
        }
#pragma unroll
        for (int off = 32; off; off >>= 1)
#pragma unroll
            for (int hh = 0; hh < HH; hh++) s[hh] += __shfl_xor(s[hh], off);
#pragma unroll
        for (int hh = 0; hh < HH; hh++) {
            float inv = 1.0f / s[hh];
            ushort4 pk;
            pk.x = f2bf(e[hh][0] * inv);
            pk.y = f2bf(e[hh][1] * inv);
            pk.z = f2bf(e[hh][2] * inv);
            pk.w = f2bf(e[hh][3] * inv);
            int off2 = hh * 8192 + ii * 512 + ((j0 * 2) ^ ((ii & 7) << 4));
            *(ushort4*)(at_lds + off2) = pk;
        }
    }
    __syncthreads();

    // ---- phase C: wave = head w: hp[16 x 128] = attn[16 x 256] @ Wht^T
    int w = wave;
    int row = lane & 15, g = lane >> 4;
    short8 af[8];
#pragma unroll
    for (int ks = 0; ks < 8; ks++) {
        int off = w * 8192 + row * 512 + ((ks * 64 + g * 16) ^ ((row & 7) << 4));
        af[ks] = *(const short8*)(at_lds + off);
    }
    __syncthreads();   // all af in regs; at_lds now reusable for hp

    f32x4 acc[8];
#pragma unroll
    for (int ft = 0; ft < 8; ft++) acc[ft] = (f32x4)(0.f);
    const unsigned short* whb = Wht + (size_t)(b * HH + w) * OF * NN;
#pragma unroll
    for (int ft = 0; ft < 8; ft++) {
        const unsigned short* wb = whb + (size_t)(ft * 16 + row) * NN + g * 8;
#pragma unroll
        for (int ks = 0; ks < 8; ks++) {
            short8 bf = *(const short8*)(wb + ks * 32);
            acc[ft] = MFMA16(af[ks], bf, acc[ft]);
        }
    }
    // hp -> bf16 into at_lds (swizzled 1024B rows); i = g*4+r, kf = w*128+ft*16+row
#pragma unroll
    for (int ft = 0; ft < 8; ft++)
#pragma unroll
        for (int r = 0; r < 4; r++) {
            int i = g * 4 + r;
            int kf = w * 128 + ft * 16 + row;
            int off = i * 1024 + ((kf * 2) ^ ((i & 7) << 4));
            *(unsigned short*)(at_lds + off) = f2bf(acc[ft][r]);
        }
    __syncthreads();

    // ---- phase D: out[16 x 128] = elu(hp[16 x 512] @ Wc[512 x 128])
    short8 ah[16];
#pragma unroll
    for (int ks = 0; ks < 16; ks++) {
        int off = row * 1024 + ((ks * 64 + g * 16) ^ ((row & 7) << 4));
        ah[ks] = *(const short8*)(at_lds + off);
    }
    f32x4 o2[2];
    o2[0] = (f32x4)(0.f); o2[1] = (f32x4)(0.f);
#pragma unroll
    for (int ct = 0; ct < 2; ct++) {
        int c = (w * 2 + ct) * 16 + row;
        const unsigned short* wc = Wct + (size_t)c * 512 + g * 8;
#pragma unroll
        for (int ks = 0; ks < 16; ks++) {
            short8 bf = *(const short8*)(wc + ks * 32);
            o2[ct] = MFMA16(ah[ks], bf, o2[ct]);
        }
    }
#pragma unroll
    for (int ct = 0; ct < 2; ct++)
#pragma unroll
        for (int r = 0; r < 4; r++) {
            float v = o2[ct][r];
            v = v > 0.f ? v : expm1f(v);
            int i = i0 + g * 4 + r;
            int c = (w * 2 + ct) * 16 + row;
            out[((size_t)b * NN + i) * OF + c] = v;
        }
}

extern "C" void kernel_launch(void* const* d_in, const int* in_sizes, int n_in,
                              void* d_out, int out_size, void* d_ws, size_t ws_size,
                              hipStream_t stream) {
    const float* h      = (const float*)d_in[0];
    const float* proj   = (const float*)d_in[1];
    const float* sim    = (const float*)d_in[2];
    const int*   qm     = (const int*)d_in[3];
    const float* W      = (const float*)d_in[4];
    const float* a      = (const float*)d_in[5];
    const float* w_proj = (const float*)d_in[6];
    const float* w_sim  = (const float*)d_in[7];
    const float* qbias  = (const float*)d_in[8];
    const float* Wc     = (const float*)d_in[9];
    float* out = (float*)d_out;

    unsigned short* Wt  = (unsigned short*)d_ws;               // 65,536 elems
    unsigned short* Wct = Wt + 512 * 128;                      // 65,536
    unsigned short* Wht = Wct + 128 * 512;                     // 8,388,608
    float* ei = (float*)(Wht + (size_t)BB * HH * OF * NN);
    float* ej = ei + (size_t)BB * HH * NN;
    float* sp = ej + (size_t)BB * HH * NN;
    float* ss = sp + (size_t)BB * HH * NN;
    unsigned char* qidx = (unsigned char*)(ss + (size_t)BB * HH * NN);  // 4,194,304 B

    k0_prep<<<2088, 256, 0, stream>>>(qm, W, Wc, qidx, Wt, Wct);
    k1_wh<<<512, 256, 0, stream>>>(h, Wt, a, w_proj, w_sim, Wht, ei, ej, sp, ss);
    k2_fused<<<BB * 16, 256, 0, stream>>>(proj, sim, qidx, qbias, ei, ej, sp, ss, Wht, Wct, out);
}

// Round 6
// 190.442 us; speedup vs baseline: 1.0423x; 1.0423x over previous
//
#include <hip/hip_runtime.h>
#include <math.h>

#define BB 64
#define NN 256
#define IN_F 128
#define OF 128
#define HH 4
#define NEG_SLOPE 0.2f

typedef __attribute__((ext_vector_type(8))) short short8;
typedef __attribute__((ext_vector_type(4))) float f32x4;

#define MFMA16(a, b, c) __builtin_amdgcn_mfma_f32_16x16x32_bf16(a, b, c, 0, 0, 0)

// float -> bf16 bits, round-to-nearest-even (finite)
__device__ inline unsigned short f2bf(float x) {
    unsigned u = __float_as_uint(x);
    u += 0x7fff + ((u >> 16) & 1);
    return (unsigned short)(u >> 16);
}

// ---------------- K0: W/Wc transposes only ----------------
// blocks [0,8): W[128k][512f] -> Wt[512f][128k] bf16
// blocks [8,40): Wc[512k][128c] -> Wct[128c][512k] bf16
__global__ __launch_bounds__(256) void k0_prep(const float* __restrict__ W,
        const float* __restrict__ Wc, unsigned short* __restrict__ Wt,
        unsigned short* __restrict__ Wct) {
    __shared__ float hl[16][516];
    int blk = blockIdx.x, t = threadIdx.x;
    if (blk < 8) {
        int k0 = blk * 16;
#pragma unroll
        for (int it = 0; it < 8; it++) {         // stage 16x512 f32, coalesced
            int li = it * 256 + t;
            int row = li >> 7, col4 = li & 127;
            float4 v = ((const float4*)(W + (size_t)(k0 + row) * 512))[col4];
            *(float4*)&hl[row][col4 * 4] = v;
        }
        __syncthreads();
#pragma unroll
        for (int cc = 0; cc < 2; cc++) {         // write Wt rows: 32B contiguous per f
            int c = t * 2 + cc;
            short8 s0, s1;
#pragma unroll
            for (int k = 0; k < 8; k++) s0[k] = (short)f2bf(hl[k][c]);
#pragma unroll
            for (int k = 0; k < 8; k++) s1[k] = (short)f2bf(hl[k + 8][c]);
            unsigned short* dst = Wt + (size_t)c * 128 + k0;
            *(short8*)dst = s0;
            *(short8*)(dst + 8) = s1;
        }
    } else {
        int k0 = (blk - 8) * 16;
#pragma unroll
        for (int it = 0; it < 2; it++) {         // stage 16x128 f32
            int li = it * 256 + t;
            int row = li >> 5, col4 = li & 31;
            float4 v = ((const float4*)(Wc + (size_t)(k0 + row) * 128))[col4];
            *(float4*)&hl[row][col4 * 4] = v;
        }
        __syncthreads();
        if (t < 128) {
            int c = t;
            short8 s0, s1;
#pragma unroll
            for (int k = 0; k < 8; k++) s0[k] = (short)f2bf(hl[k][c]);
#pragma unroll
            for (int k = 0; k < 8; k++) s1[k] = (short)f2bf(hl[k + 8][c]);
            unsigned short* dst = Wct + (size_t)c * 512 + k0;
            *(short8*)dst = s0;
            *(short8*)(dst + 8) = s1;
        }
    }
}

// ---------------- K1: Wht[f][n] = (h@W)^T via MFMA, packed 8B stores ----------
__global__ __launch_bounds__(256) void k1_wh(const float* __restrict__ h,
        const unsigned short* __restrict__ Wt, const float* __restrict__ a,
        const float* __restrict__ w_proj, const float* __restrict__ w_sim,
        unsigned short* __restrict__ Wht, float* __restrict__ ei,
        float* __restrict__ ej, float* __restrict__ sp, float* __restrict__ ss) {
    __shared__ __align__(16) unsigned char hs[8192];   // 32 rows x 256B, XOR-swizzled
    __shared__ float a1s[512], a2s[512], wps[128], wss[128];
    int l = blockIdx.x;
    int b = l >> 3, n0 = (l & 7) * 32;
    int t = threadIdx.x;
    for (int idx = t; idx < 512; idx += 256) {
        int hh = idx >> 7, f = idx & 127;
        a1s[idx] = a[hh * 256 + f];
        a2s[idx] = a[hh * 256 + 128 + f];
    }
    if (t < 128) { wps[t] = w_proj[t]; wss[t] = w_sim[t]; }
    {   // stage h rows n0..n0+31 as bf16, coalesced f32 loads
        const float4* hsrc = (const float4*)(h + ((size_t)b * NN + n0) * IN_F);
#pragma unroll
        for (int it = 0; it < 4; it++) {
            int li = it * 256 + t;
            float4 v = hsrc[li];
            int row = li >> 5, col4 = li & 31;
            ushort4 o;
            o.x = f2bf(v.x); o.y = f2bf(v.y); o.z = f2bf(v.z); o.w = f2bf(v.w);
            *(ushort4*)(hs + row * 256 + ((col4 * 8) ^ ((row & 7) << 4))) = o;
        }
    }
    __syncthreads();

    int w = t >> 6, lane = t & 63;
    int cc = lane & 15, g = lane >> 4;

    short8 bh[2][4];
#pragma unroll
    for (int tn = 0; tn < 2; tn++) {
        int row = tn * 16 + cc;
#pragma unroll
        for (int ks = 0; ks < 4; ks++)
            bh[tn][ks] = *(const short8*)(hs + row * 256 + ((ks * 64 + g * 16) ^ ((row & 7) << 4)));
    }

    float q[2][4][4] = {{{0.f}}};
    unsigned short* whb = Wht + (size_t)(b * HH + w) * OF * NN;

#pragma unroll
    for (int tf = 0; tf < 8; tf++) {
        int f = tf * 16 + cc;
        short8 aw[4];
#pragma unroll
        for (int ks = 0; ks < 4; ks++)
            aw[ks] = *(const short8*)(Wt + (size_t)(w * 128 + f) * IN_F + ks * 32 + g * 8);
        f32x4 acc[2];
        acc[0] = (f32x4)(0.f); acc[1] = (f32x4)(0.f);
#pragma unroll
        for (int ks = 0; ks < 4; ks++) {
            acc[0] = MFMA16(bh[0][ks], aw[ks], acc[0]);
            acc[1] = MFMA16(bh[1][ks], aw[ks], acc[1]);
        }
        float c1 = a1s[w * 128 + f], c2 = a2s[w * 128 + f];
        float c3 = wps[f], c4 = wss[f];
#pragma unroll
        for (int tn = 0; tn < 2; tn++) {
            ushort4 o;
            o.x = f2bf(acc[tn][0]); o.y = f2bf(acc[tn][1]);
            o.z = f2bf(acc[tn][2]); o.w = f2bf(acc[tn][3]);
            *(ushort4*)(whb + (size_t)f * NN + n0 + tn * 16 + g * 4) = o;
#pragma unroll
            for (int r = 0; r < 4; r++) {
                float v = acc[tn][r];
                q[tn][0][r] += v * c1; q[tn][1][r] += v * c2;
                q[tn][2][r] += v * c3; q[tn][3][r] += v * c4;
            }
        }
    }
#pragma unroll
    for (int tn = 0; tn < 2; tn++)
#pragma unroll
        for (int ty = 0; ty < 4; ty++)
#pragma unroll
            for (int r = 0; r < 4; r++) {
                float v = q[tn][ty][r];
                v += __shfl_xor(v, 1); v += __shfl_xor(v, 2);
                v += __shfl_xor(v, 4); v += __shfl_xor(v, 8);
                q[tn][ty][r] = v;
            }
    if (cc == 0) {
#pragma unroll
        for (int tn = 0; tn < 2; tn++) {
            size_t base = (size_t)(b * HH + w) * NN + n0 + tn * 16 + g * 4;
            *(float4*)&ei[base] = make_float4(q[tn][0][0], q[tn][0][1], q[tn][0][2], q[tn][0][3]);
            *(float4*)&ej[base] = make_float4(q[tn][1][0], q[tn][1][1], q[tn][1][2], q[tn][1][3]);
            *(float4*)&sp[base] = make_float4(q[tn][2][0], q[tn][2][1], q[tn][2][2], q[tn][2][3]);
            *(float4*)&ss[base] = make_float4(q[tn][3][0], q[tn][3][1], q[tn][3][2], q[tn][3][3]);
        }
    }
}

// ---------------- KB: e + softmax -> attn_g (bf16), pure streaming ----------
// grid = B*16, block 256. Wave owns 4 rows; lane owns j = lane*4..+3.
// LDS ~5KB, one barrier -> high occupancy.
__global__ __launch_bounds__(256) void kb_attn(
        const float* __restrict__ proj, const float* __restrict__ sim,
        const int* __restrict__ qm, const float* __restrict__ qbias,
        const float* __restrict__ ei, const float* __restrict__ ej,
        const float* __restrict__ sp, const float* __restrict__ ss,
        unsigned short* __restrict__ attn_g) {
    __shared__ __align__(16) float ejs[1024];
    __shared__ float eis[HH][16], sps[HH][16], sss[HH][16];
    __shared__ float qb_s[16];
    int l = blockIdx.x;
    int b = l >> 4;
    int i0 = (l & 15) * 16;
    int t = threadIdx.x;
    int wave = t >> 6, lane = t & 63;

    for (int c = t; c < HH * NN; c += 256)
        ejs[c] = ej[(size_t)b * HH * NN + c];
    if (t < 64) {
        int hh = t >> 4, ii = t & 15;
        size_t base = ((size_t)b * HH + hh) * NN + i0 + ii;
        eis[hh][ii] = ei[base]; sps[hh][ii] = sp[base]; sss[hh][ii] = ss[base];
    }
    if (t < 16) qb_s[t] = qbias[t];
    __syncthreads();

    int j0 = lane * 4;
    for (int rr = 0; rr < 4; rr++) {
        int ii = wave * 4 + rr;
        int i = i0 + ii;
        size_t rb = ((size_t)b * NN + i) * NN + j0;
        float4 P4 = *(const float4*)&proj[rb];
        float4 S4 = *(const float4*)&sim[rb];
        int4 qa = *(const int4*)&qm[rb * 2];
        int4 qc = *(const int4*)&qm[rb * 2 + 4];
        float qb0 = qb_s[qa.x * 4 + qa.y], qb1 = qb_s[qa.z * 4 + qa.w];
        float qb2 = qb_s[qc.x * 4 + qc.y], qb3 = qb_s[qc.z * 4 + qc.w];
        float e[HH][4];
#pragma unroll
        for (int hh = 0; hh < HH; hh++) {
            float4 ej4 = *(const float4*)&ejs[hh * 256 + j0];
            float bi = eis[hh][ii], spv = sps[hh][ii], ssv = sss[hh][ii];
            float x;
            x = bi + ej4.x; x = x > 0.f ? x : NEG_SLOPE * x; e[hh][0] = x + spv * P4.x + ssv * S4.x + qb0;
            x = bi + ej4.y; x = x > 0.f ? x : NEG_SLOPE * x; e[hh][1] = x + spv * P4.y + ssv * S4.y + qb1;
            x = bi + ej4.z; x = x > 0.f ? x : NEG_SLOPE * x; e[hh][2] = x + spv * P4.z + ssv * S4.z + qb2;
            x = bi + ej4.w; x = x > 0.f ? x : NEG_SLOPE * x; e[hh][3] = x + spv * P4.w + ssv * S4.w + qb3;
        }
        float mx[HH];
#pragma unroll
        for (int hh = 0; hh < HH; hh++)
            mx[hh] = fmaxf(fmaxf(e[hh][0], e[hh][1]), fmaxf(e[hh][2], e[hh][3]));
#pragma unroll
        for (int off = 32; off; off >>= 1)
#pragma unroll
            for (int hh = 0; hh < HH; hh++)
                mx[hh] = fmaxf(mx[hh], __shfl_xor(mx[hh], off));
        float s[HH];
#pragma unroll
        for (int hh = 0; hh < HH; hh++) {
            e[hh][0] = __expf(e[hh][0] - mx[hh]);
            e[hh][1] = __expf(e[hh][1] - mx[hh]);
            e[hh][2] = __expf(e[hh][2] - mx[hh]);
            e[hh][3] = __expf(e[hh][3] - mx[hh]);
            s[hh] = (e[hh][0] + e[hh][1]) + (e[hh][2] + e[hh][3]);
        }
#pragma unroll
        for (int off = 32; off; off >>= 1)
#pragma unroll
            for (int hh = 0; hh < HH; hh++) s[hh] += __shfl_xor(s[hh], off);
#pragma unroll
        for (int hh = 0; hh < HH; hh++) {
            float inv = 1.0f / s[hh];
            ushort4 pk;
            pk.x = f2bf(e[hh][0] * inv);
            pk.y = f2bf(e[hh][1] * inv);
            pk.z = f2bf(e[hh][2] * inv);
            pk.w = f2bf(e[hh][3] * inv);
            *(ushort4*)(attn_g + (((size_t)b * HH + hh) * NN + i) * NN + j0) = pk;
        }
    }
}

// ---------------- KC: hp = attn @ Wh (MFMA), out = elu(hp @ Wc) (MFMA) --------
// grid = B*16 (XCD-remapped), wave = head. LDS 16KB -> high occupancy.
__global__ __launch_bounds__(256) void kc_pv(
        const unsigned short* __restrict__ attn_g,
        const unsigned short* __restrict__ Wht, const unsigned short* __restrict__ Wct,
        float* __restrict__ out) {
    __shared__ __align__(16) char hp_lds[16384];   // hp bf16 [16][512], XOR-swizzled rows
    int l = blockIdx.x;                  // XCD-bijective remap: 16 chunks of b co-located
    int xcd = l & 7, m = l >> 3;
    int b = xcd + ((m >> 4) << 3);
    int i0 = (m & 15) * 16;
    int t = threadIdx.x;
    int w = t >> 6, lane = t & 63;
    int row = lane & 15, g = lane >> 4;

    // A-frags: attn[b][w][i0+row][k], k = ks*32 + g*8
    const unsigned short* ab = attn_g + (((size_t)b * HH + w) * NN + i0 + row) * NN + g * 8;
    short8 af[8];
#pragma unroll
    for (int ks = 0; ks < 8; ks++)
        af[ks] = *(const short8*)(ab + ks * 32);

    f32x4 acc[8];
#pragma unroll
    for (int ft = 0; ft < 8; ft++) acc[ft] = (f32x4)(0.f);
    const unsigned short* whb = Wht + (size_t)(b * HH + w) * OF * NN;
#pragma unroll
    for (int ft = 0; ft < 8; ft++) {
        const unsigned short* wb = whb + (size_t)(ft * 16 + row) * NN + g * 8;
#pragma unroll
        for (int ks = 0; ks < 8; ks++) {
            short8 bf = *(const short8*)(wb + ks * 32);
            acc[ft] = MFMA16(af[ks], bf, acc[ft]);
        }
    }
    // hp -> bf16 LDS (swizzled 1024B rows); i = g*4+r, kf = w*128 + ft*16 + row
#pragma unroll
    for (int ft = 0; ft < 8; ft++)
#pragma unroll
        for (int r = 0; r < 4; r++) {
            int i = g * 4 + r;
            int kf = w * 128 + ft * 16 + row;
            int off = i * 1024 + ((kf * 2) ^ ((i & 7) << 4));
            *(unsigned short*)(hp_lds + off) = f2bf(acc[ft][r]);
        }
    __syncthreads();

    // out[16 x 128] = elu(hp[16 x 512] @ Wc[512 x 128])
    short8 ah[16];
#pragma unroll
    for (int ks = 0; ks < 16; ks++) {
        int off = row * 1024 + ((ks * 64 + g * 16) ^ ((row & 7) << 4));
        ah[ks] = *(const short8*)(hp_lds + off);
    }
    f32x4 o2[2];
    o2[0] = (f32x4)(0.f); o2[1] = (f32x4)(0.f);
#pragma unroll
    for (int ct = 0; ct < 2; ct++) {
        int c = (w * 2 + ct) * 16 + row;
        const unsigned short* wc = Wct + (size_t)c * 512 + g * 8;
#pragma unroll
        for (int ks = 0; ks < 16; ks++) {
            short8 bf = *(const short8*)(wc + ks * 32);
            o2[ct] = MFMA16(ah[ks], bf, o2[ct]);
        }
    }
#pragma unroll
    for (int ct = 0; ct < 2; ct++)
#pragma unroll
        for (int r = 0; r < 4; r++) {
            float v = o2[ct][r];
            v = v > 0.f ? v : expm1f(v);
            int i = i0 + g * 4 + r;
            int c = (w * 2 + ct) * 16 + row;
            out[((size_t)b * NN + i) * OF + c] = v;
        }
}

extern "C" void kernel_launch(void* const* d_in, const int* in_sizes, int n_in,
                              void* d_out, int out_size, void* d_ws, size_t ws_size,
                              hipStream_t stream) {
    const float* h      = (const float*)d_in[0];
    const float* proj   = (const float*)d_in[1];
    const float* sim    = (const float*)d_in[2];
    const int*   qm     = (const int*)d_in[3];
    const float* W      = (const float*)d_in[4];
    const float* a      = (const float*)d_in[5];
    const float* w_proj = (const float*)d_in[6];
    const float* w_sim  = (const float*)d_in[7];
    const float* qbias  = (const float*)d_in[8];
    const float* Wc     = (const float*)d_in[9];
    float* out = (float*)d_out;

    unsigned short* Wt  = (unsigned short*)d_ws;               // 65,536 elems
    unsigned short* Wct = Wt + 512 * 128;                      // 65,536
    unsigned short* Wht = Wct + 128 * 512;                     // 8,388,608
    float* ei = (float*)(Wht + (size_t)BB * HH * OF * NN);
    float* ej = ei + (size_t)BB * HH * NN;
    float* sp = ej + (size_t)BB * HH * NN;
    float* ss = sp + (size_t)BB * HH * NN;
    unsigned short* attn_g = (unsigned short*)(ss + (size_t)BB * HH * NN);  // 16,777,216 elems

    k0_prep<<<40, 256, 0, stream>>>(W, Wc, Wt, Wct);
    k1_wh<<<512, 256, 0, stream>>>(h, Wt, a, w_proj, w_sim, Wht, ei, ej, sp, ss);
    kb_attn<<<BB * 16, 256, 0, stream>>>(proj, sim, qm, qbias, ei, ej, sp, ss, attn_g);
    kc_pv<<<BB * 16, 256, 0, stream>>>(attn_g, Wht, Wct, out);
}